// Round 10
// baseline (350.899 us; speedup 1.0000x reference)
//
#include <hip/hip_runtime.h>
#include <stdint.h>

// EfficientSelfAttention on MI355X (gfx950). External I/O FP32; internals bf16
// MFMA. B=4, T=4096, D=1024, H=8, Dh=128. Scratch in __device__ globals.
// R16: gemm_kv re-tiled 256^2 -> 128x256, BK=32, 8 waves, per-wave 64x64
//      (acc[4][4]=64 AGPR; ~<=128 unified regs -> 4 waves/SIMD) with 64KB
//      LDS -> 2 blocks/CU co-resident. Mechanism: R8=R13=R14 plateau at 30%
//      MfmaUtil was register-closed 2-waves/SIMD barrier lockstep; R15's 25%
//      mask-skip was 2-round quantized. Co-residency fills stalls AND the
//      1024-block grid makes the skip granularity fine (768 work / 512 slots).
//      New conflict-free swizzle for 64B rows (chunk ^ ((row>>1)&3), checked
//      bank-exact for all quads). Flags now 128-token granular (g_mflag[128]).
//      qy / att / attnorm / prep structurally unchanged (flag indices only).

typedef unsigned short u16;
typedef __attribute__((ext_vector_type(8))) short bf16x8;
typedef __attribute__((ext_vector_type(4))) float f32x4;

// ------------------------------------------------------- device workspace
__device__ u16 g_WT[3][1024 * 1024];   // 6 MiB: WqT, WkT, WvT (bf16)
__device__ u16 g_xn[16777216];         // 32 MiB
__device__ u16 g_ekT[16777216];        // 32 MiB  [b][d][t]
__device__ u16 g_vvT[16777216];        // 32 MiB  [b][l][t]
__device__ float g_attp[8388608];      // 32 MiB  [kc*32+bh][d*128+l], 8 chunks used
__device__ u16 g_attT[524288];         // 1 MiB   [bh][l*128+d]
__device__ float g_Z[4096];            //         [b*1024+d]
__device__ int g_mflag[128];           // any(mask>0.5) per 128-token block

__device__ __forceinline__ float b2f(u16 u) {
  union { unsigned int i; float f; } c;
  c.i = ((unsigned int)u) << 16;
  return c.f;
}
__device__ __forceinline__ u16 f2b(float f) {
  union { float f; unsigned int i; } c;
  c.f = f;
  unsigned int r = c.i + 0x7fffu + ((c.i >> 16) & 1u);
  return (u16)(r >> 16);
}

__device__ __forceinline__ void gload16(const void* g, void* l) {
  __builtin_amdgcn_global_load_lds(
      reinterpret_cast<const __attribute__((address_space(1))) uint32_t*>(
          reinterpret_cast<uintptr_t>(g)),
      reinterpret_cast<__attribute__((address_space(3))) uint32_t*>(
          reinterpret_cast<uintptr_t>(l)),
      16, 0, 0);
}

// Stage 128x32 bf16 tile (row stride `stride` elems) into 8KB LDS [128][32].
// (used by gemm_att)
__device__ __forceinline__ void stage128x32(const u16* g, int stride, char* lds,
                                            int wave, int lane) {
  const int r = wave * 32 + (lane >> 2);
  const int cb = (lane & 3) * 16;
  const char* gp = (const char*)g;
  gload16(gp + (size_t)r * stride * 2 + cb, lds + wave * 2048);
  gload16(gp + (size_t)(r + 16) * stride * 2 + cb, lds + wave * 2048 + 1024);
}

// A/B fragment from [128][32] LDS tile: row `row`, k = (lane>>4)*8 .. +7
__device__ __forceinline__ bf16x8 frag_ld(const char* lds, int row, int lane) {
  return *(const bf16x8*)(lds + row * 64 + ((lane >> 4) * 16));
}

// 16 MFMA on one staged 128x32 A/B tile pair (gemm_att).
__device__ __forceinline__ void tile_mfma(const char* As, const char* Bs,
                                          f32x4 (&acc)[4][4], int wm, int wn,
                                          int lane) {
  bf16x8 af[4], bfr[4];
#pragma unroll
  for (int i = 0; i < 4; i++) af[i] = frag_ld(As, wm * 64 + i * 16 + (lane & 15), lane);
#pragma unroll
  for (int j = 0; j < 4; j++) bfr[j] = frag_ld(Bs, wn * 64 + j * 16 + (lane & 15), lane);
#pragma unroll
  for (int i = 0; i < 4; i++)
#pragma unroll
    for (int j = 0; j < 4; j++)
      acc[i][j] = __builtin_amdgcn_mfma_f32_16x16x32_bf16(af[i], bfr[j], acc[i][j], 0, 0, 0);
}

// ---------------- 256^2 helpers (gemm_qy ph1) — 128B rows, chunk^(row&7) ----
__device__ __forceinline__ void stageA256(char* buf, const u16* gsrc, int h,
                                          int wave, int lane) {
#pragma unroll
  for (int i = 0; i < 2; i++) {
    const int ib = i * 64 + wave * 8;  // idx base (wave-uniform)
    const int rowb = (ib & 63) | ((ib & 64) << 1) | (h << 6);
    const int row = rowb + (lane >> 3);
    const int cc = (lane & 7) ^ (row & 7);  // inverse-swizzled source chunk
    gload16((const char*)gsrc + ((size_t)row * 1024 + cc * 8) * 2,
            buf + rowb * 128);
  }
}
__device__ __forceinline__ void stageB256(char* buf, const u16* gsrc, int h,
                                          int wave, int lane) {
#pragma unroll
  for (int i = 0; i < 2; i++) {
    const int ib = i * 64 + wave * 8;
    const int rowb = (ib & 31) | ((ib & 96) << 1) | (h << 5);
    const int row = rowb + (lane >> 3);
    const int cc = (lane & 7) ^ (row & 7);
    gload16((const char*)gsrc + ((size_t)row * 1024 + cc * 8) * 2,
            buf + rowb * 128);
  }
}
__device__ __forceinline__ bf16x8 fragS(const char* buf, int R, int ks, int lane) {
  const int q = lane >> 4;
  return *(const bf16x8*)(buf + R * 128 + ((((ks << 2) + q) ^ (R & 7)) << 4));
}

// One 256^2 K-tile, ONE phase (qy ph1; R14-measured == R8's 4-phase).
template <bool ST>
__device__ __forceinline__ void tile_1ph(char* Ab, char* Bb, char* An, char* Bn,
                                         const u16* Agn, const u16* Bgn,
                                         f32x4 (&acc)[8][4], int wave, int lane,
                                         int wm, int wn) {
  if constexpr (ST) {
    stageA256(An, Agn, 0, wave, lane);
    stageA256(An, Agn, 1, wave, lane);
    stageB256(Bn, Bgn, 0, wave, lane);
    stageB256(Bn, Bgn, 1, wave, lane);
  }
  bf16x8 a[4][2], b[4][2];
#pragma unroll
  for (int cf = 0; cf < 4; cf++) {
    const int R = wn * 64 + cf * 16 + (lane & 15);
#pragma unroll
    for (int ks = 0; ks < 2; ks++) b[cf][ks] = fragS(Bb, R, ks, lane);
  }
#pragma unroll
  for (int rf = 0; rf < 4; rf++) {
    const int R = wm * 128 + rf * 16 + (lane & 15);
#pragma unroll
    for (int ks = 0; ks < 2; ks++) a[rf][ks] = fragS(Ab, R, ks, lane);
  }
  __builtin_amdgcn_s_setprio(1);
#pragma unroll
  for (int rf = 0; rf < 4; rf++)
#pragma unroll
    for (int cf = 0; cf < 4; cf++)
#pragma unroll
      for (int ks = 0; ks < 2; ks++)
        acc[rf][cf] = __builtin_amdgcn_mfma_f32_16x16x32_bf16(
            a[rf][ks], b[cf][ks], acc[rf][cf], 0, 0, 0);
  bf16x8 a2[4][2];
#pragma unroll
  for (int rf = 0; rf < 4; rf++) {
    const int R = wm * 128 + 64 + rf * 16 + (lane & 15);
#pragma unroll
    for (int ks = 0; ks < 2; ks++) a2[rf][ks] = fragS(Ab, R, ks, lane);
  }
#pragma unroll
  for (int rf = 0; rf < 4; rf++)
#pragma unroll
    for (int cf = 0; cf < 4; cf++)
#pragma unroll
      for (int ks = 0; ks < 2; ks++)
        acc[4 + rf][cf] = __builtin_amdgcn_mfma_f32_16x16x32_bf16(
            a2[rf][ks], b[cf][ks], acc[4 + rf][cf], 0, 0, 0);
  __builtin_amdgcn_s_setprio(0);
  if constexpr (ST) asm volatile("s_waitcnt vmcnt(0)" ::: "memory");
  __builtin_amdgcn_s_barrier();
  __builtin_amdgcn_sched_barrier(0);
}

// ---------------- 128x256 helpers (gemm_kv) — 64B rows, chunk^((row>>1)&3) --
// A tile [128][32] bf16 (8KB), B tile [256][32] bf16 (16KB). Stage: linear
// LDS dest + inverse-swizzled global chunk. Read: swizzled ds_read. Bank-
// checked: each 16-lane quad's b128 reads cover all 32 banks 2-way (free).
__device__ __forceinline__ void stageA128(char* buf, const u16* gsrc,
                                          int wave, int lane) {
  const int row = wave * 16 + (lane >> 2);
  const int cc = (lane & 3) ^ ((row >> 1) & 3);
  gload16((const char*)gsrc + ((size_t)row * 1024 + cc * 8) * 2,
          buf + wave * 1024);
}
__device__ __forceinline__ void stageB256x32(char* buf, const u16* gsrc,
                                             int wave, int lane) {
#pragma unroll
  for (int i = 0; i < 2; i++) {
    const int row = i * 128 + wave * 16 + (lane >> 2);
    const int cc = (lane & 3) ^ ((row >> 1) & 3);
    gload16((const char*)gsrc + ((size_t)row * 1024 + cc * 8) * 2,
            buf + i * 8192 + wave * 1024);
  }
}
__device__ __forceinline__ bf16x8 fragS32(const char* buf, int R, int lane) {
  const int q = lane >> 4;
  return *(const bf16x8*)(buf + R * 64 + (((q ^ ((R >> 1) & 3))) << 4));
}

// kv K-tile (K=32), one phase. acc[4][4] per wave (64x64 out tile).
template <bool ST>
__device__ __forceinline__ void tile32(char* Ab, char* Bb, char* An, char* Bn,
                                       const u16* Agn, const u16* Bgn,
                                       f32x4 (&acc)[4][4], int wave, int lane,
                                       int wm, int wn) {
  if constexpr (ST) {
    stageA128(An, Agn, wave, lane);
    stageB256x32(Bn, Bgn, wave, lane);
  }
  bf16x8 a[4], b[4];
#pragma unroll
  for (int cf = 0; cf < 4; cf++)
    b[cf] = fragS32(Bb, wn * 64 + cf * 16 + (lane & 15), lane);
#pragma unroll
  for (int rf = 0; rf < 4; rf++)
    a[rf] = fragS32(Ab, wm * 64 + rf * 16 + (lane & 15), lane);
  __builtin_amdgcn_s_setprio(1);
#pragma unroll
  for (int rf = 0; rf < 4; rf++)
#pragma unroll
    for (int cf = 0; cf < 4; cf++)
      acc[rf][cf] = __builtin_amdgcn_mfma_f32_16x16x32_bf16(
          a[rf], b[cf], acc[rf][cf], 0, 0, 0);
  __builtin_amdgcn_s_setprio(0);
  if constexpr (ST) asm volatile("s_waitcnt vmcnt(0)" ::: "memory");
  __builtin_amdgcn_s_barrier();
  __builtin_amdgcn_sched_barrier(0);
}

// ---------------------------- prep: LN (blocks 0..16383) + W transpose (rest)
// Blocks 0..127 also compute g_mflag[bid] = any(mask[bid*128..+127]>0.5).
__global__ __launch_bounds__(256) void prep_kernel(const float* __restrict__ x,
                                                   const float* __restrict__ gamma,
                                                   const float* __restrict__ beta,
                                                   const float* __restrict__ wq,
                                                   const float* __restrict__ wk,
                                                   const float* __restrict__ wv,
                                                   const float* __restrict__ mask) {
  __shared__ float ls[4], ls2[4];
  __shared__ u16 tile[32][33];
  __shared__ int sflag;
  const int bid = blockIdx.x;
  const int tid = threadIdx.x;
  if (bid < 16384) {
    if (bid < 16) g_Z[bid * 256 + tid] = 0.0f;  // per-launch Z reset
    if (bid < 128) {
      if (tid == 0) sflag = 0;
      __syncthreads();
      if (tid < 128 && mask[bid * 128 + tid] > 0.5f) atomicOr(&sflag, 1);
      __syncthreads();
      if (tid == 0) g_mflag[bid] = sflag;
    }
    const int wave = tid >> 6, lane = tid & 63;
    const float* xr = x + (size_t)bid * 1024;
    float4 u = ((const float4*)xr)[tid];
    float v0 = u.x, v1 = u.y, v2 = u.z, v3 = u.w;
    float s = v0 + v1 + v2 + v3;
    float s2 = v0 * v0 + v1 * v1 + v2 * v2 + v3 * v3;
#pragma unroll
    for (int off = 32; off > 0; off >>= 1) {
      s += __shfl_down(s, off);
      s2 += __shfl_down(s2, off);
    }
    if (lane == 0) { ls[wave] = s; ls2[wave] = s2; }
    __syncthreads();
    s = ls[0] + ls[1] + ls[2] + ls[3];
    s2 = ls2[0] + ls2[1] + ls2[2] + ls2[3];
    const float mu = s * (1.0f / 1024.0f);
    const float var = fmaxf(s2 * (1.0f / 1024.0f) - mu * mu, 0.0f);
    const float rstd = rsqrtf(var + 1e-5f);
    float4 g4 = ((const float4*)gamma)[tid];
    float4 be = ((const float4*)beta)[tid];
    ushort4 o;
    o.x = f2b((v0 - mu) * rstd * g4.x + be.x);
    o.y = f2b((v1 - mu) * rstd * g4.y + be.y);
    o.z = f2b((v2 - mu) * rstd * g4.z + be.z);
    o.w = f2b((v3 - mu) * rstd * g4.w + be.w);
    *(ushort4*)(g_xn + (size_t)bid * 1024 + tid * 4) = o;
  } else {
    const int id = bid - 16384;
    const int which = id >> 10;
    const int rem = id & 1023;
    const float* src = (which == 0) ? wq : (which == 1) ? wk : wv;
    u16* dst = g_WT[which];
    const int tx = tid & 31;
    const int ty = tid >> 5;
    const int c0 = (rem & 31) * 32, r0 = (rem >> 5) * 32;
#pragma unroll
    for (int i = 0; i < 4; i++)
      tile[ty + i * 8][tx] = f2b(src[(size_t)(r0 + ty + i * 8) * 1024 + c0 + tx]);
    __syncthreads();
#pragma unroll
    for (int i = 0; i < 4; i++)
      dst[(size_t)(c0 + ty + i * 8) * 1024 + r0 + tx] = tile[tx][ty + i * 8];
  }
}

// --------------------------------------------------------------- K/V GEMM
// 128x256 tile, BK=32, 1-phase loop, 2 blocks/CU target. Grid 1024 =
// 128 m-tiles x 8 n-variants. XCD swizzle: c=L&7 -> mt = c + 8*((L>>3)>>3);
// nv = (L>>3)&7; n0 = (nv&3)*256; z = nv>>2.
// z=0: ekT = (m>0.5)?exp(xn@Wk^T+bk):0 (+fused Z); z=1: vvT = (xn@Wv^T+bv)*m
// Fully-masked 128-token tiles (g_mflag==0) write zeros and exit.
__global__ __launch_bounds__(512, 4) void gemm_kv(const float* __restrict__ bk,
                                                  const float* __restrict__ bv,
                                                  const float* __restrict__ mask) {
  __shared__ __align__(16) char smem[65536];
  const int tid = threadIdx.x, wave = tid >> 6, lane = tid & 63;
  const int L = blockIdx.x;
  const int g = L >> 3;
  const int mt = (L & 7) + 8 * (g >> 3);
  const int nv = g & 7;
  const int n0 = (nv & 3) * 256;
  const int z = nv >> 2;
  const int m0 = mt * 128;
  const u16* wt = z ? g_WT[2] : g_WT[1];
  const float* bias = z ? bv : bk;
  u16* outT = z ? g_vvT : g_ekT;
  const int b = m0 >> 12;
  const int t0 = m0 & 4095;
  const int wm = wave >> 2, wn = wave & 3;
  const u16* Ag = g_xn + (size_t)m0 * 1024;
  const u16* Bg = wt + (size_t)n0 * 1024;
  const size_t gbase = (size_t)b * (1024 * 4096) + (size_t)n0 * 4096 + t0;

  if (!g_mflag[m0 >> 7]) {  // fully-masked -> exact zeros
    const uint4 zz = {0u, 0u, 0u, 0u};
#pragma unroll
    for (int u = 0; u < 8; u++) {
      const int id = u * 512 + tid;
      const int feat = id >> 4, c = id & 15;
      *(uint4*)(outT + gbase + (size_t)feat * 4096 + c * 8) = zz;
    }
    return;
  }

  char* A0 = smem;            // 8KB
  char* B0 = smem + 8192;     // 16KB
  char* A1 = smem + 24576;    // 8KB
  char* B1 = smem + 32768;    // 16KB
  f32x4 zero = {0.f, 0.f, 0.f, 0.f};
  f32x4 acc[4][4];
#pragma unroll
  for (int i = 0; i < 4; i++)
#pragma unroll
    for (int j = 0; j < 4; j++) acc[i][j] = zero;

  // prologue: stage tile 0 into buffer 0, full drain (once)
  stageA128(A0, Ag, wave, lane);
  stageB256x32(B0, Bg, wave, lane);
  asm volatile("s_waitcnt vmcnt(0)" ::: "memory");
  __builtin_amdgcn_s_barrier();

#pragma unroll 1
  for (int t = 0; t < 31; ++t) {
    const int p = t & 1;
    tile32<true>(p ? A1 : A0, p ? B1 : B0, p ? A0 : A1, p ? B0 : B1,
                 Ag + (t + 1) * 32, Bg + (t + 1) * 32, acc, wave, lane, wm, wn);
  }
  tile32<false>(A1, B1, A0, B0, Ag, Bg, acc, wave, lane, wm, wn);

  // epilogue: bias + mask/exp, fused zrow, transpose via swizzled LDS, store.
  // tT[256 feat][128 tok], chunk swizzle ^ (feat&15) (16 chunks of 8 toks).
  u16* tT = (u16*)smem;
  float fsum[4] = {0.f, 0.f, 0.f, 0.f};
#pragma unroll
  for (int rf = 0; rf < 4; rf++)
#pragma unroll
    for (int r = 0; r < 4; r++) {
      const int tok = wm * 64 + rf * 16 + (lane >> 4) * 4 + r;
      const float mv = mask[m0 + tok];
#pragma unroll
      for (int cf = 0; cf < 4; cf++) {
        const int feat = wn * 64 + cf * 16 + (lane & 15);
        const float aV = acc[rf][cf][r] + bias[n0 + feat];
        float o;
        if (z)
          o = aV * mv;
        else
          o = (mv > 0.5f) ? __expf(fminf(aV, 30.0f)) : 0.0f;
        const u16 ob = f2b(o);
        tT[feat * 128 + ((((tok >> 3) ^ (feat & 15)) << 3) | (tok & 7))] = ob;
        if (!z) fsum[cf] += b2f(ob);  // sum rounded values == zrow semantics
      }
    }
  if (!z) {
#pragma unroll
    for (int cf = 0; cf < 4; cf++) {
      float s = fsum[cf];
      s += __shfl_xor(s, 16);
      s += __shfl_xor(s, 32);
      if (lane < 16)
        atomicAdd(&g_Z[b * 1024 + n0 + wn * 64 + cf * 16 + lane], s);
    }
  }
  __syncthreads();
#pragma unroll
  for (int u = 0; u < 8; u++) {
    const int id = u * 512 + tid;
    const int feat = id >> 4, c = id & 15;
    uint4 val = *(const uint4*)&tT[feat * 128 + ((c ^ (feat & 15)) << 3)];
    *(uint4*)(outT + gbase + (size_t)feat * 4096 + c * 8) = val;
  }
}

// ------------------------------------------------------------- att GEMM
// 8 chunks of K=512: attp[kc][bh][d][l] = sum_{t in 512-chunk kc}
// ekT[b][h*128+d][t] * vvT[b][h*128+l][t].  Grid (8, 32) = 256 blocks.
// Chunks with no valid tokens contribute exactly 0 -> early return.
__global__ __launch_bounds__(256) void gemm_att() {
  __shared__ __align__(16) char smem[32768];
  char* A0 = smem;
  char* B0 = smem + 8192;
  char* A1 = smem + 16384;
  char* B1 = smem + 24576;
  const int tid = threadIdx.x, wave = tid >> 6, lane = tid & 63;
  const int kc = blockIdx.x;  // 0..7
  const int bh = blockIdx.y;  // 0..31
  const int b = bh >> 3, h = bh & 7;
  const int f0 = b * 32 + kc * 4;
  if (!(g_mflag[f0] | g_mflag[f0 + 1] | g_mflag[f0 + 2] | g_mflag[f0 + 3]))
    return;
  const size_t base = (size_t)b * (1024 * 4096) + (size_t)(h * 128) * 4096;
  const int wm = wave & 1, wn = wave >> 1;
  const u16* Ag = g_ekT + base + kc * 512;
  const u16* Bg = g_vvT + base + kc * 512;

  f32x4 zero = {0.f, 0.f, 0.f, 0.f};
  f32x4 acc[4][4];
#pragma unroll
  for (int i = 0; i < 4; i++)
#pragma unroll
    for (int j = 0; j < 4; j++) acc[i][j] = zero;

  stage128x32(Ag, 4096, A0, wave, lane);
  stage128x32(Bg, 4096, B0, wave, lane);
  __syncthreads();
  for (int kt = 0; kt < 512; kt += 64) {
    stage128x32(Ag + kt + 32, 4096, A1, wave, lane);
    stage128x32(Bg + kt + 32, 4096, B1, wave, lane);
    tile_mfma(A0, B0, acc, wm, wn, lane);
    __syncthreads();
    if (kt + 64 < 512) {
      stage128x32(Ag + kt + 64, 4096, A0, wave, lane);
      stage128x32(Bg + kt + 64, 4096, B0, wave, lane);
    }
    tile_mfma(A1, B1, acc, wm, wn, lane);
    __syncthreads();
  }

  float* op = g_attp + ((size_t)(kc * 32 + bh)) * 16384;
#pragma unroll
  for (int i = 0; i < 4; i++)
#pragma unroll
    for (int r = 0; r < 4; r++) {
      const int row = wm * 64 + i * 16 + (lane >> 4) * 4 + r;
#pragma unroll
      for (int j = 0; j < 4; j++) {
        const int col = wn * 64 + j * 16 + (lane & 15);
        op[row * 128 + col] = acc[i][j][r];
      }
    }
}

// ------------------------------------- reduce partials, /Z, store attT[bh][l][d]
__global__ __launch_bounds__(256) void attnorm_kernel() {
  const int bh = blockIdx.x;
  const int b = bh >> 3, h = bh & 7;
  const int tid = threadIdx.x;
  __shared__ float Zl[128];
  __shared__ int vfl[8];
  if (tid < 128) Zl[tid] = fmaxf(g_Z[b * 1024 + h * 128 + tid], 1e-30f);
  if (tid < 8) {
    const int f0 = b * 32 + tid * 4;
    vfl[tid] = g_mflag[f0] | g_mflag[f0 + 1] | g_mflag[f0 + 2] | g_mflag[f0 + 3];
  }
  __syncthreads();
  const int i0 = blockIdx.y * 2048;
  for (int i = i0 + tid; i < i0 + 2048; i += 256) {
    const int d = i >> 7, l = i & 127;
    float s = 0.f;
#pragma unroll
    for (int c = 0; c < 8; c++)
      if (vfl[c]) s += g_attp[((size_t)(c * 32 + bh)) * 16384 + i];
    g_attT[(size_t)bh * 16384 + l * 128 + d] = f2b(s / Zl[d]);
  }
}

// ---------------------------------------------------------- fused q + y
// 256^2 1-phase ph1 over the FULL feature dim (tile = 2 heads). Grid 256.
// ph1: q = xn @ WqT (K=1024). Then ph2 attT B-frags prefetched; epilogue-1:
// exp(q+bq) -> swizzled qs[256][256] in LDS + per-head row sums (zq4).
// ph2: y = P @ attT (K=128, 2 heads). Epilogue-2: out = x + y/zq.
__global__ __launch_bounds__(512, 2) void gemm_qy(const float* __restrict__ bq,
                                                  const float* __restrict__ x,
                                                  float* __restrict__ out) {
  __shared__ __align__(16) char smem[131072];
  __shared__ float zq4[4][256];
  const int tid = threadIdx.x, wave = tid >> 6, lane = tid & 63;
  const int L = blockIdx.x;
  const int g = L >> 3;
  const int mt = (L & 7) + 8 * (g >> 2);
  const int n0 = (g & 3) * 256;
  const int m0 = mt * 256;
  const int b = m0 >> 12;
  const int wm = wave >> 2, wn = wave & 3;
  const u16* Ag = g_xn + (size_t)m0 * 1024;
  const u16* Bg = g_WT[0] + (size_t)n0 * 1024;

  f32x4 zero = {0.f, 0.f, 0.f, 0.f};
  f32x4 acc[8][4];
#pragma unroll
  for (int i = 0; i < 8; i++)
#pragma unroll
    for (int j = 0; j < 4; j++) acc[i][j] = zero;

  // prologue
  stageA256(smem, Ag, 0, wave, lane);
  stageA256(smem, Ag, 1, wave, lane);
  stageB256(smem + 65536, Bg, 0, wave, lane);
  stageB256(smem + 65536, Bg, 1, wave, lane);
  asm volatile("s_waitcnt vmcnt(0)" ::: "memory");
  __builtin_amdgcn_s_barrier();

#pragma unroll 1
  for (int t = 0; t < 15; ++t) {
    const int p = t & 1;
    tile_1ph<true>(smem + p * 32768, smem + 65536 + p * 32768,
                   smem + (p ^ 1) * 32768, smem + 65536 + (p ^ 1) * 32768,
                   Ag + (t + 1) * 64, Bg + (t + 1) * 64, acc, wave, lane, wm, wn);
  }
  tile_1ph<false>(smem + 32768, smem + 65536 + 32768, smem, smem + 65536, Ag,
                  Bg, acc, wave, lane, wm, wn);

  // prefetch ALL ph2 B-fragments from global attT now; their L2 latency
  // hides under epilogue-1's exp/shuffle VALU work (no LDS needed).
  const int hl = wn >> 1;                      // head within the 2-head pair
  const int bhh = b * 8 + (n0 >> 7) + hl;
  const u16* attb = g_attT + ((size_t)bhh << 14);
  bf16x8 bpre[4][4];
#pragma unroll
  for (int ks = 0; ks < 4; ks++)
#pragma unroll
    for (int cf = 0; cf < 4; cf++) {
      const int l = (wn & 1) * 64 + cf * 16 + (lane & 15);  // out col (in head)
      bpre[ks][cf] = *(const bf16x8*)(attb + l * 128 + ks * 32 + (lane >> 4) * 8);
    }

  // epilogue-1: e = exp(q + bq) (clamped); write swizzled qs[tok][feat] into
  // the freed smem (slot = (feat>>3) ^ (tok&31), bijective per row); per-head
  // row-sums into zq4[wn][tok] (each wave's 64 cols lie in ONE head).
  u16* qs = (u16*)smem;
#pragma unroll
  for (int rf = 0; rf < 8; rf++)
#pragma unroll
    for (int r = 0; r < 4; r++) {
      const int tok = wm * 128 + rf * 16 + (lane >> 4) * 4 + r;
      float rs = 0.f;
#pragma unroll
      for (int cf = 0; cf < 4; cf++) {
        const int f = wn * 64 + cf * 16 + (lane & 15);
        const float e = __expf(fminf(acc[rf][cf][r] + bq[n0 + f], 30.0f));
        qs[tok * 256 + ((((f >> 3) ^ (tok & 31)) << 3) | (f & 7))] = f2b(e);
        rs += e;
      }
      rs += __shfl_xor(rs, 1);
      rs += __shfl_xor(rs, 2);
      rs += __shfl_xor(rs, 4);
      rs += __shfl_xor(rs, 8);
      if ((lane & 15) == 0) zq4[wn][tok] = rs;
    }
  __syncthreads();

  // phase 2: y[tok, col] = sum_d P[tok, hl*128+d] * attT[bhh][l*128 + d].
  // A-frags from swizzled qs (chunk = hl*16 + ks*4 + q); B from bpre regs.
  f32x4 acc2[8][4];
#pragma unroll
  for (int i = 0; i < 8; i++)
#pragma unroll
    for (int j = 0; j < 4; j++) acc2[i][j] = zero;

#pragma unroll
  for (int ks = 0; ks < 4; ks++) {
    bf16x8 af[8];
#pragma unroll
    for (int rf = 0; rf < 8; rf++) {
      const int tok = wm * 128 + rf * 16 + (lane & 15);
      af[rf] = *(const bf16x8*)&qs[tok * 256 +
          ((((hl << 4) + (ks << 2) + (lane >> 4)) ^ (tok & 31)) << 3)];
    }
#pragma unroll
    for (int rf = 0; rf < 8; rf++)
#pragma unroll
      for (int cf = 0; cf < 4; cf++)
        acc2[rf][cf] = __builtin_amdgcn_mfma_f32_16x16x32_bf16(
            af[rf], bpre[ks][cf], acc2[rf][cf], 0, 0, 0);
  }

  // epilogue-2: out = x + y / zq  (fp32)
#pragma unroll
  for (int rf = 0; rf < 8; rf++)
#pragma unroll
    for (int r = 0; r < 4; r++) {
      const int tok = wm * 128 + rf * 16 + (lane >> 4) * 4 + r;
      const float zq =
          fmaxf(zq4[hl * 2][tok] + zq4[hl * 2 + 1][tok], 1e-30f);
      const size_t n = (size_t)(m0 + tok);
#pragma unroll
      for (int cf = 0; cf < 4; cf++) {
        const int f = wn * 64 + cf * 16 + (lane & 15);
        const size_t idx = n * 1024 + n0 + f;
        out[idx] = x[idx] + acc2[rf][cf][r] / zq;
      }
    }
}

// ----------------------------------------------------------------- launch
extern "C" void kernel_launch(void* const* d_in, const int* in_sizes, int n_in,
                              void* d_out, int out_size, void* d_ws, size_t ws_size,
                              hipStream_t stream) {
  const float* x = (const float*)d_in[0];
  const float* mask = (const float*)d_in[1];
  const float* Wq = (const float*)d_in[2];
  const float* bq = (const float*)d_in[3];
  const float* Wk = (const float*)d_in[4];
  const float* bk = (const float*)d_in[5];
  const float* Wv = (const float*)d_in[6];
  const float* bv = (const float*)d_in[7];
  const float* gamma = (const float*)d_in[8];
  const float* beta = (const float*)d_in[9];
  float* out = (float*)d_out;
  (void)d_ws; (void)ws_size;

  prep_kernel<<<dim3(16384 + 3072), 256, 0, stream>>>(x, gamma, beta, Wq, Wk, Wv, mask);
  gemm_kv<<<dim3(1024), 512, 0, stream>>>(bk, bv, mask);
  gemm_att<<<dim3(8, 32), 256, 0, stream>>>();
  attnorm_kernel<<<dim3(32, 8), 256, 0, stream>>>();
  gemm_qy<<<dim3(256), 512, 0, stream>>>(bq, x, out);
}

// Round 11
// 320.071 us; speedup vs baseline: 1.0963x; 1.0963x over previous
//
#include <hip/hip_runtime.h>
#include <stdint.h>

// EfficientSelfAttention on MI355X (gfx950). External I/O FP32; internals bf16
// MFMA. B=4, T=4096, D=1024, H=8, Dh=128. Scratch in __device__ globals.
// R17: FUSION — kv re-partitioned to (256 tokens x 1 head) blocks computing
//      BOTH k-proj and v-proj (same total MFMA), then the head's att partial
//      locally: ek/vv are transposed into LDS (the old epilogue transpose),
//      a local K=256 GEMM produces attp[tt][bh][128][128], and ekT/vvT are
//      NEVER materialized in HBM. Deletes gemm_att and 128MB of traffic
//      (64 write + 64 read). Masked 256-token tiles skip with zero writes
//      (attnorm sums only flagged chunks). kv schedule itself = R14 1-phase
//      (R8==R13==R14==93us showed schedule variants are equivalent here).
//      R16's BK=32 retile regressed (99.5us) and is reverted.

typedef unsigned short u16;
typedef __attribute__((ext_vector_type(8))) short bf16x8;
typedef __attribute__((ext_vector_type(4))) float f32x4;

// ------------------------------------------------------- device workspace
__device__ u16 g_WT[3][1024 * 1024];   // 6 MiB: WqT, WkT, WvT (bf16)
__device__ u16 g_xn[16777216];         // 32 MiB
__device__ float g_attp[8388608];      // 32 MiB  [tt*32+bh][d*128+l], 16 chunks
__device__ u16 g_attT[524288];         // 1 MiB   [bh][l*128+d]
__device__ float g_Z[4096];            //         [b*1024+d]
__device__ int g_mflag[64];            // any(mask>0.5) per 256-token block

__device__ __forceinline__ float b2f(u16 u) {
  union { unsigned int i; float f; } c;
  c.i = ((unsigned int)u) << 16;
  return c.f;
}
__device__ __forceinline__ u16 f2b(float f) {
  union { float f; unsigned int i; } c;
  c.f = f;
  unsigned int r = c.i + 0x7fffu + ((c.i >> 16) & 1u);
  return (u16)(r >> 16);
}

__device__ __forceinline__ void gload16(const void* g, void* l) {
  __builtin_amdgcn_global_load_lds(
      reinterpret_cast<const __attribute__((address_space(1))) uint32_t*>(
          reinterpret_cast<uintptr_t>(g)),
      reinterpret_cast<__attribute__((address_space(3))) uint32_t*>(
          reinterpret_cast<uintptr_t>(l)),
      16, 0, 0);
}

// ---------------- [N][64]-bf16 LDS tiles, 128B rows, chunk^(row&7) swizzle --
// Stage: linear LDS dest (global_load_lds requirement) + inverse-swizzled
// per-lane GLOBAL source chunk. Read: swizzled ds_read. (rule #21)
__device__ __forceinline__ void stageA256(char* buf, const u16* gsrc, int h,
                                          int wave, int lane) {
#pragma unroll
  for (int i = 0; i < 2; i++) {
    const int ib = i * 64 + wave * 8;  // idx base (wave-uniform)
    const int rowb = (ib & 63) | ((ib & 64) << 1) | (h << 6);
    const int row = rowb + (lane >> 3);
    const int cc = (lane & 7) ^ (row & 7);  // inverse-swizzled source chunk
    gload16((const char*)gsrc + ((size_t)row * 1024 + cc * 8) * 2,
            buf + rowb * 128);
  }
}
__device__ __forceinline__ void stageB256(char* buf, const u16* gsrc, int h,
                                          int wave, int lane) {
#pragma unroll
  for (int i = 0; i < 2; i++) {
    const int ib = i * 64 + wave * 8;
    const int rowb = (ib & 31) | ((ib & 96) << 1) | (h << 5);
    const int row = rowb + (lane >> 3);
    const int cc = (lane & 7) ^ (row & 7);
    gload16((const char*)gsrc + ((size_t)row * 1024 + cc * 8) * 2,
            buf + rowb * 128);
  }
}
// [128][64] tile (Wk/Wv head slice), rows 0..127
__device__ __forceinline__ void stageC128(char* buf, const u16* gsrc,
                                          int wave, int lane) {
#pragma unroll
  for (int i = 0; i < 2; i++) {
    const int rowb = i * 64 + wave * 8;
    const int row = rowb + (lane >> 3);
    const int cc = (lane & 7) ^ (row & 7);
    gload16((const char*)gsrc + ((size_t)row * 1024 + cc * 8) * 2,
            buf + rowb * 128);
  }
}
// frag read: row R (includes lane&15), k-step ks: global chunk = ks*4 + q
__device__ __forceinline__ bf16x8 fragS(const char* buf, int R, int ks, int lane) {
  const int q = lane >> 4;
  return *(const bf16x8*)(buf + R * 128 + ((((ks << 2) + q) ^ (R & 7)) << 4));
}

// One 256^2 qy K-tile, ONE phase (R14; measured == R8's 4-phase).
template <bool ST>
__device__ __forceinline__ void tile_1ph(char* Ab, char* Bb, char* An, char* Bn,
                                         const u16* Agn, const u16* Bgn,
                                         f32x4 (&acc)[8][4], int wave, int lane,
                                         int wm, int wn) {
  if constexpr (ST) {
    stageA256(An, Agn, 0, wave, lane);
    stageA256(An, Agn, 1, wave, lane);
    stageB256(Bn, Bgn, 0, wave, lane);
    stageB256(Bn, Bgn, 1, wave, lane);
  }
  bf16x8 a[4][2], b[4][2];
#pragma unroll
  for (int cf = 0; cf < 4; cf++) {
    const int R = wn * 64 + cf * 16 + (lane & 15);
#pragma unroll
    for (int ks = 0; ks < 2; ks++) b[cf][ks] = fragS(Bb, R, ks, lane);
  }
#pragma unroll
  for (int rf = 0; rf < 4; rf++) {
    const int R = wm * 128 + rf * 16 + (lane & 15);
#pragma unroll
    for (int ks = 0; ks < 2; ks++) a[rf][ks] = fragS(Ab, R, ks, lane);
  }
  __builtin_amdgcn_s_setprio(1);
#pragma unroll
  for (int rf = 0; rf < 4; rf++)
#pragma unroll
    for (int cf = 0; cf < 4; cf++)
#pragma unroll
      for (int ks = 0; ks < 2; ks++)
        acc[rf][cf] = __builtin_amdgcn_mfma_f32_16x16x32_bf16(
            a[rf][ks], b[cf][ks], acc[rf][cf], 0, 0, 0);
  bf16x8 a2[4][2];
#pragma unroll
  for (int rf = 0; rf < 4; rf++) {
    const int R = wm * 128 + 64 + rf * 16 + (lane & 15);
#pragma unroll
    for (int ks = 0; ks < 2; ks++) a2[rf][ks] = fragS(Ab, R, ks, lane);
  }
#pragma unroll
  for (int rf = 0; rf < 4; rf++)
#pragma unroll
    for (int cf = 0; cf < 4; cf++)
#pragma unroll
      for (int ks = 0; ks < 2; ks++)
        acc[4 + rf][cf] = __builtin_amdgcn_mfma_f32_16x16x32_bf16(
            a2[rf][ks], b[cf][ks], acc[4 + rf][cf], 0, 0, 0);
  __builtin_amdgcn_s_setprio(0);
  if constexpr (ST) asm volatile("s_waitcnt vmcnt(0)" ::: "memory");
  __builtin_amdgcn_s_barrier();
  __builtin_amdgcn_sched_barrier(0);
}

// kva K-tile: A[256][64] shared, dual B[128][64] (Wk,Wv). Per wave: 128tok x
// 32feat for EACH of ek/vv -> acc_e[8][2], acc_v[8][2]. 64 MFMA/wave/tile
// (same as the old single-GEMM 256^2 tile). One phase, one barrier.
template <bool ST>
__device__ __forceinline__ void tile_kv(char* Ab, char* Bkb, char* Bvb,
                                        char* An, char* Bkn, char* Bvn,
                                        const u16* Agn, const u16* Bkgn,
                                        const u16* Bvgn, f32x4 (&ae)[8][2],
                                        f32x4 (&av)[8][2], int wave, int lane,
                                        int wm, int wn) {
  if constexpr (ST) {
    stageA256(An, Agn, 0, wave, lane);
    stageA256(An, Agn, 1, wave, lane);
    stageC128(Bkn, Bkgn, wave, lane);
    stageC128(Bvn, Bvgn, wave, lane);
  }
  bf16x8 bk[2][2], bv[2][2];
#pragma unroll
  for (int cf = 0; cf < 2; cf++) {
    const int R = wn * 32 + cf * 16 + (lane & 15);
#pragma unroll
    for (int ks = 0; ks < 2; ks++) {
      bk[cf][ks] = fragS(Bkb, R, ks, lane);
      bv[cf][ks] = fragS(Bvb, R, ks, lane);
    }
  }
  bf16x8 a[4][2];
#pragma unroll
  for (int rf = 0; rf < 4; rf++) {
    const int R = wm * 128 + rf * 16 + (lane & 15);
#pragma unroll
    for (int ks = 0; ks < 2; ks++) a[rf][ks] = fragS(Ab, R, ks, lane);
  }
  __builtin_amdgcn_s_setprio(1);
#pragma unroll
  for (int rf = 0; rf < 4; rf++)
#pragma unroll
    for (int cf = 0; cf < 2; cf++)
#pragma unroll
      for (int ks = 0; ks < 2; ks++) {
        ae[rf][cf] = __builtin_amdgcn_mfma_f32_16x16x32_bf16(
            a[rf][ks], bk[cf][ks], ae[rf][cf], 0, 0, 0);
        av[rf][cf] = __builtin_amdgcn_mfma_f32_16x16x32_bf16(
            a[rf][ks], bv[cf][ks], av[rf][cf], 0, 0, 0);
      }
  bf16x8 a2[4][2];
#pragma unroll
  for (int rf = 0; rf < 4; rf++) {
    const int R = wm * 128 + 64 + rf * 16 + (lane & 15);
#pragma unroll
    for (int ks = 0; ks < 2; ks++) a2[rf][ks] = fragS(Ab, R, ks, lane);
  }
#pragma unroll
  for (int rf = 0; rf < 4; rf++)
#pragma unroll
    for (int cf = 0; cf < 2; cf++)
#pragma unroll
      for (int ks = 0; ks < 2; ks++) {
        ae[4 + rf][cf] = __builtin_amdgcn_mfma_f32_16x16x32_bf16(
            a2[rf][ks], bk[cf][ks], ae[4 + rf][cf], 0, 0, 0);
        av[4 + rf][cf] = __builtin_amdgcn_mfma_f32_16x16x32_bf16(
            a2[rf][ks], bv[cf][ks], av[4 + rf][cf], 0, 0, 0);
      }
  __builtin_amdgcn_s_setprio(0);
  if constexpr (ST) asm volatile("s_waitcnt vmcnt(0)" ::: "memory");
  __builtin_amdgcn_s_barrier();
  __builtin_amdgcn_sched_barrier(0);
}

// ---------------------------- prep: LN (blocks 0..16383) + W transpose (rest)
// Blocks 0..63 also compute g_mflag[bid] = any(mask[bid*256..+255]>0.5).
__global__ __launch_bounds__(256) void prep_kernel(const float* __restrict__ x,
                                                   const float* __restrict__ gamma,
                                                   const float* __restrict__ beta,
                                                   const float* __restrict__ wq,
                                                   const float* __restrict__ wk,
                                                   const float* __restrict__ wv,
                                                   const float* __restrict__ mask) {
  __shared__ float ls[4], ls2[4];
  __shared__ u16 tile[32][33];
  __shared__ int sflag;
  const int bid = blockIdx.x;
  const int tid = threadIdx.x;
  if (bid < 16384) {
    if (bid < 16) g_Z[bid * 256 + tid] = 0.0f;  // per-launch Z reset
    if (bid < 64) {
      if (tid == 0) sflag = 0;
      __syncthreads();
      if (mask[bid * 256 + tid] > 0.5f) atomicOr(&sflag, 1);
      __syncthreads();
      if (tid == 0) g_mflag[bid] = sflag;
    }
    const int wave = tid >> 6, lane = tid & 63;
    const float* xr = x + (size_t)bid * 1024;
    float4 u = ((const float4*)xr)[tid];
    float v0 = u.x, v1 = u.y, v2 = u.z, v3 = u.w;
    float s = v0 + v1 + v2 + v3;
    float s2 = v0 * v0 + v1 * v1 + v2 * v2 + v3 * v3;
#pragma unroll
    for (int off = 32; off > 0; off >>= 1) {
      s += __shfl_down(s, off);
      s2 += __shfl_down(s2, off);
    }
    if (lane == 0) { ls[wave] = s; ls2[wave] = s2; }
    __syncthreads();
    s = ls[0] + ls[1] + ls[2] + ls[3];
    s2 = ls2[0] + ls2[1] + ls2[2] + ls2[3];
    const float mu = s * (1.0f / 1024.0f);
    const float var = fmaxf(s2 * (1.0f / 1024.0f) - mu * mu, 0.0f);
    const float rstd = rsqrtf(var + 1e-5f);
    float4 g4 = ((const float4*)gamma)[tid];
    float4 be = ((const float4*)beta)[tid];
    ushort4 o;
    o.x = f2b((v0 - mu) * rstd * g4.x + be.x);
    o.y = f2b((v1 - mu) * rstd * g4.y + be.y);
    o.z = f2b((v2 - mu) * rstd * g4.z + be.z);
    o.w = f2b((v3 - mu) * rstd * g4.w + be.w);
    *(ushort4*)(g_xn + (size_t)bid * 1024 + tid * 4) = o;
  } else {
    const int id = bid - 16384;
    const int which = id >> 10;
    const int rem = id & 1023;
    const float* src = (which == 0) ? wq : (which == 1) ? wk : wv;
    u16* dst = g_WT[which];
    const int tx = tid & 31;
    const int ty = tid >> 5;
    const int c0 = (rem & 31) * 32, r0 = (rem >> 5) * 32;
#pragma unroll
    for (int i = 0; i < 4; i++)
      tile[ty + i * 8][tx] = f2b(src[(size_t)(r0 + ty + i * 8) * 1024 + c0 + tx]);
    __syncthreads();
#pragma unroll
    for (int i = 0; i < 4; i++)
      dst[(size_t)(c0 + ty + i * 8) * 1024 + r0 + tx] = tile[tx][ty + i * 8];
  }
}

// --------------------------------------------- fused K/V projection + att
// Grid 512 = 64 (b,tt) x 8 heads. L = bt + 64*h so the 8 same-A-slab blocks
// sit on one XCD (L%8 == bt%8). Per block: 256 tokens x head h.
//   ek[t][f] = (m>0.5)?exp(xn@WkT+bk):0 ; vv[t][f] = (xn@WvT+bv)*m
//   -> transpose both into LDS (bf16, chunk^feat swizzle), fused Z atomics,
//   -> local GEMM attp_chunk[d][l] = sum_{t in tile} ekT[d][t]*vvT[l][t]
// Fully-masked tiles exit immediately (attnorm skips their chunks).
__global__ __launch_bounds__(512, 2) void gemm_kva(const float* __restrict__ bk,
                                                   const float* __restrict__ bv,
                                                   const float* __restrict__ mask) {
  __shared__ __align__(16) char smem[131072];
  const int tid = threadIdx.x, wave = tid >> 6, lane = tid & 63;
  const int L = blockIdx.x;
  const int bt = L & 63;           // (b,tt): b = bt>>4, tt = bt&15
  const int h = L >> 6;            // head 0..7
  const int m0 = bt * 256;
  const int b = m0 >> 12;
  const int tt = bt & 15;
  if (!g_mflag[bt]) return;        // exact-zero chunk; attnorm skips it

  const int wm = wave >> 2, wn = wave & 3;
  const u16* Ag = g_xn + (size_t)m0 * 1024;
  const u16* Bkg = g_WT[1] + (size_t)(h * 128) * 1024;
  const u16* Bvg = g_WT[2] + (size_t)(h * 128) * 1024;

  // LDS: dbuf {A 32K, Bk 16K, Bv 16K} x2 = 128K; epilogue reuses as
  // ekT[128][256] (64K) + vvT[128][256] (64K).
  char* A0 = smem;
  char* Bk0 = smem + 32768;
  char* Bv0 = smem + 49152;
  char* A1 = smem + 65536;
  char* Bk1 = smem + 98304;
  char* Bv1 = smem + 114688;

  f32x4 zero = {0.f, 0.f, 0.f, 0.f};
  f32x4 ae[8][2], av[8][2];
#pragma unroll
  for (int i = 0; i < 8; i++)
#pragma unroll
    for (int j = 0; j < 2; j++) { ae[i][j] = zero; av[i][j] = zero; }

  // prologue: stage tile 0 into buffer 0, full drain (once)
  stageA256(A0, Ag, 0, wave, lane);
  stageA256(A0, Ag, 1, wave, lane);
  stageC128(Bk0, Bkg, wave, lane);
  stageC128(Bv0, Bvg, wave, lane);
  asm volatile("s_waitcnt vmcnt(0)" ::: "memory");
  __builtin_amdgcn_s_barrier();

#pragma unroll 1
  for (int t = 0; t < 15; ++t) {
    const int p = t & 1;
    tile_kv<true>(p ? A1 : A0, p ? Bk1 : Bk0, p ? Bv1 : Bv0,
                  p ? A0 : A1, p ? Bk0 : Bk1, p ? Bv0 : Bv1,
                  Ag + (t + 1) * 64, Bkg + (t + 1) * 64, Bvg + (t + 1) * 64,
                  ae, av, wave, lane, wm, wn);
  }
  tile_kv<false>(A1, Bk1, Bv1, A0, Bk0, Bv0, Ag, Bkg, Bvg, ae, av, wave, lane,
                 wm, wn);

  // epilogue-1: bias + exp/mask, transpose into LDS (ekT, vvT), fused Z.
  // ekT/vvT rows = feat (0..127), 256 toks/row; chunk slot = (tok>>3)^(feat&31).
  u16* ekT = (u16*)smem;             // 64KB (over buffer0 — reads retired)
  u16* vvT = (u16*)(smem + 65536);   // 64KB (over buffer1 — retired at last barrier)
  float fsum[2] = {0.f, 0.f};
#pragma unroll
  for (int rf = 0; rf < 8; rf++)
#pragma unroll
    for (int r = 0; r < 4; r++) {
      const int tok = wm * 128 + rf * 16 + (lane >> 4) * 4 + r;
      const float mv = mask[m0 + tok];
#pragma unroll
      for (int cf = 0; cf < 2; cf++) {
        const int feat = wn * 32 + cf * 16 + (lane & 15);  // 0..127 in-head
        const int slot = (((tok >> 3) ^ (feat & 31)) << 3) | (tok & 7);
        const float ve = ae[rf][cf][r] + bk[h * 128 + feat];
        const float oe = (mv > 0.5f) ? __expf(fminf(ve, 30.0f)) : 0.0f;
        const u16 eb = f2b(oe);
        ekT[feat * 256 + slot] = eb;
        fsum[cf] += b2f(eb);  // sum rounded values == zrow semantics
        const float vv = (av[rf][cf][r] + bv[h * 128 + feat]) * mv;
        vvT[feat * 256 + slot] = f2b(vv);
      }
    }
#pragma unroll
  for (int cf = 0; cf < 2; cf++) {
    float s = fsum[cf];
    s += __shfl_xor(s, 16);
    s += __shfl_xor(s, 32);
    if (lane < 16)
      atomicAdd(&g_Z[b * 1024 + h * 128 + wn * 32 + cf * 16 + lane], s);
  }
  __syncthreads();

  // epilogue-2: local GEMM att[d][l] = sum_t ekT[d][t]*vvT[l][t], K=256.
  // Per wave: 64(d-half: wm) x 32(l-quarter: wn) output, acc2[4][2].
  f32x4 acc2[4][2];
#pragma unroll
  for (int i = 0; i < 4; i++)
#pragma unroll
    for (int j = 0; j < 2; j++) acc2[i][j] = zero;
#pragma unroll
  for (int ks = 0; ks < 8; ks++) {
    bf16x8 aF[4], bF[2];
#pragma unroll
    for (int rf = 0; rf < 4; rf++) {
      const int d = wm * 64 + rf * 16 + (lane & 15);
      aF[rf] = *(const bf16x8*)&ekT[d * 256 +
          ((((ks << 2) + (lane >> 4)) ^ (d & 31)) << 3)];
    }
#pragma unroll
    for (int cf = 0; cf < 2; cf++) {
      const int l = wn * 32 + cf * 16 + (lane & 15);
      bF[cf] = *(const bf16x8*)&vvT[l * 256 +
          ((((ks << 2) + (lane >> 4)) ^ (l & 31)) << 3)];
    }
#pragma unroll
    for (int rf = 0; rf < 4; rf++)
#pragma unroll
      for (int cf = 0; cf < 2; cf++)
        acc2[rf][cf] = __builtin_amdgcn_mfma_f32_16x16x32_bf16(
            aF[rf], bF[cf], acc2[rf][cf], 0, 0, 0);
  }

  float* op = g_attp + (size_t)(tt * 32 + b * 8 + h) * 16384;
#pragma unroll
  for (int rf = 0; rf < 4; rf++)
#pragma unroll
    for (int r = 0; r < 4; r++) {
      const int d = wm * 64 + rf * 16 + (lane >> 4) * 4 + r;
#pragma unroll
      for (int cf = 0; cf < 2; cf++) {
        const int l = wn * 32 + cf * 16 + (lane & 15);
        op[d * 128 + l] = acc2[rf][cf][r];
      }
    }
}

// ------------------------------------- reduce partials, /Z, store attT[bh][l][d]
__global__ __launch_bounds__(256) void attnorm_kernel() {
  const int bh = blockIdx.x;
  const int b = bh >> 3, h = bh & 7;
  const int tid = threadIdx.x;
  __shared__ float Zl[128];
  __shared__ int vfl[16];
  if (tid < 128) Zl[tid] = fmaxf(g_Z[b * 1024 + h * 128 + tid], 1e-30f);
  if (tid < 16) vfl[tid] = g_mflag[b * 16 + tid];
  __syncthreads();
  const int i0 = blockIdx.y * 2048;
  for (int i = i0 + tid; i < i0 + 2048; i += 256) {
    const int d = i >> 7, l = i & 127;
    float s = 0.f;
#pragma unroll
    for (int c = 0; c < 16; c++)
      if (vfl[c]) s += g_attp[((size_t)(c * 32 + bh)) * 16384 + i];
    g_attT[(size_t)bh * 16384 + l * 128 + d] = f2b(s / Zl[d]);
  }
}

// ---------------------------------------------------------- fused q + y
// 256^2 1-phase ph1 over the FULL feature dim (tile = 2 heads). Grid 256.
// ph1: q = xn @ WqT (K=1024). Then ph2 attT B-frags prefetched; epilogue-1:
// exp(q+bq) -> swizzled qs[256][256] in LDS + per-head row sums (zq4).
// ph2: y = P @ attT (K=128, 2 heads). Epilogue-2: out = x + y/zq.
__global__ __launch_bounds__(512, 2) void gemm_qy(const float* __restrict__ bq,
                                                  const float* __restrict__ x,
                                                  float* __restrict__ out) {
  __shared__ __align__(16) char smem[131072];
  __shared__ float zq4[4][256];
  const int tid = threadIdx.x, wave = tid >> 6, lane = tid & 63;
  const int L = blockIdx.x;
  const int g = L >> 3;
  const int mt = (L & 7) + 8 * (g >> 2);
  const int n0 = (g & 3) * 256;
  const int m0 = mt * 256;
  const int b = m0 >> 12;
  const int wm = wave >> 2, wn = wave & 3;
  const u16* Ag = g_xn + (size_t)m0 * 1024;
  const u16* Bg = g_WT[0] + (size_t)n0 * 1024;

  f32x4 zero = {0.f, 0.f, 0.f, 0.f};
  f32x4 acc[8][4];
#pragma unroll
  for (int i = 0; i < 8; i++)
#pragma unroll
    for (int j = 0; j < 4; j++) acc[i][j] = zero;

  // prologue
  stageA256(smem, Ag, 0, wave, lane);
  stageA256(smem, Ag, 1, wave, lane);
  stageB256(smem + 65536, Bg, 0, wave, lane);
  stageB256(smem + 65536, Bg, 1, wave, lane);
  asm volatile("s_waitcnt vmcnt(0)" ::: "memory");
  __builtin_amdgcn_s_barrier();

#pragma unroll 1
  for (int t = 0; t < 15; ++t) {
    const int p = t & 1;
    tile_1ph<true>(smem + p * 32768, smem + 65536 + p * 32768,
                   smem + (p ^ 1) * 32768, smem + 65536 + (p ^ 1) * 32768,
                   Ag + (t + 1) * 64, Bg + (t + 1) * 64, acc, wave, lane, wm, wn);
  }
  tile_1ph<false>(smem + 32768, smem + 65536 + 32768, smem, smem + 65536, Ag,
                  Bg, acc, wave, lane, wm, wn);

  // prefetch ALL ph2 B-fragments from global attT now; their L2 latency
  // hides under epilogue-1's exp/shuffle VALU work (no LDS needed).
  const int hl = wn >> 1;                      // head within the 2-head pair
  const int bhh = b * 8 + (n0 >> 7) + hl;
  const u16* attb = g_attT + ((size_t)bhh << 14);
  bf16x8 bpre[4][4];
#pragma unroll
  for (int ks = 0; ks < 4; ks++)
#pragma unroll
    for (int cf = 0; cf < 4; cf++) {
      const int l = (wn & 1) * 64 + cf * 16 + (lane & 15);  // out col (in head)
      bpre[ks][cf] = *(const bf16x8*)(attb + l * 128 + ks * 32 + (lane >> 4) * 8);
    }

  // epilogue-1: e = exp(q + bq) (clamped); write swizzled qs[tok][feat] into
  // the freed smem (slot = (feat>>3) ^ (tok&31), bijective per row); per-head
  // row-sums into zq4[wn][tok] (each wave's 64 cols lie in ONE head).
  u16* qs = (u16*)smem;
#pragma unroll
  for (int rf = 0; rf < 8; rf++)
#pragma unroll
    for (int r = 0; r < 4; r++) {
      const int tok = wm * 128 + rf * 16 + (lane >> 4) * 4 + r;
      float rs = 0.f;
#pragma unroll
      for (int cf = 0; cf < 4; cf++) {
        const int f = wn * 64 + cf * 16 + (lane & 15);
        const float e = __expf(fminf(acc[rf][cf][r] + bq[n0 + f], 30.0f));
        qs[tok * 256 + ((((f >> 3) ^ (tok & 31)) << 3) | (f & 7))] = f2b(e);
        rs += e;
      }
      rs += __shfl_xor(rs, 1);
      rs += __shfl_xor(rs, 2);
      rs += __shfl_xor(rs, 4);
      rs += __shfl_xor(rs, 8);
      if ((lane & 15) == 0) zq4[wn][tok] = rs;
    }
  __syncthreads();

  // phase 2: y[tok, col] = sum_d P[tok, hl*128+d] * attT[bhh][l*128 + d].
  // A-frags from swizzled qs (chunk = hl*16 + ks*4 + q); B from bpre regs.
  f32x4 acc2[8][4];
#pragma unroll
  for (int i = 0; i < 8; i++)
#pragma unroll
    for (int j = 0; j < 4; j++) acc2[i][j] = zero;

#pragma unroll
  for (int ks = 0; ks < 4; ks++) {
    bf16x8 af[8];
#pragma unroll
    for (int rf = 0; rf < 8; rf++) {
      const int tok = wm * 128 + rf * 16 + (lane & 15);
      af[rf] = *(const bf16x8*)&qs[tok * 256 +
          ((((hl << 4) + (ks << 2) + (lane >> 4)) ^ (tok & 31)) << 3)];
    }
#pragma unroll
    for (int rf = 0; rf < 8; rf++)
#pragma unroll
      for (int cf = 0; cf < 4; cf++)
        acc2[rf][cf] = __builtin_amdgcn_mfma_f32_16x16x32_bf16(
            af[rf], bpre[ks][cf], acc2[rf][cf], 0, 0, 0);
  }

  // epilogue-2: out = x + y / zq  (fp32)
#pragma unroll
  for (int rf = 0; rf < 8; rf++)
#pragma unroll
    for (int r = 0; r < 4; r++) {
      const int tok = wm * 128 + rf * 16 + (lane >> 4) * 4 + r;
      const float zq =
          fmaxf(zq4[hl * 2][tok] + zq4[hl * 2 + 1][tok], 1e-30f);
      const size_t n = (size_t)(m0 + tok);
#pragma unroll
      for (int cf = 0; cf < 4; cf++) {
        const int f = wn * 64 + cf * 16 + (lane & 15);
        const size_t idx = n * 1024 + n0 + f;
        out[idx] = x[idx] + acc2[rf][cf][r] / zq;
      }
    }
}

// ----------------------------------------------------------------- launch
extern "C" void kernel_launch(void* const* d_in, const int* in_sizes, int n_in,
                              void* d_out, int out_size, void* d_ws, size_t ws_size,
                              hipStream_t stream) {
  const float* x = (const float*)d_in[0];
  const float* mask = (const float*)d_in[1];
  const float* Wq = (const float*)d_in[2];
  const float* bq = (const float*)d_in[3];
  const float* Wk = (const float*)d_in[4];
  const float* bk = (const float*)d_in[5];
  const float* Wv = (const float*)d_in[6];
  const float* bv = (const float*)d_in[7];
  const float* gamma = (const float*)d_in[8];
  const float* beta = (const float*)d_in[9];
  float* out = (float*)d_out;
  (void)d_ws; (void)ws_size;

  prep_kernel<<<dim3(16384 + 3072), 256, 0, stream>>>(x, gamma, beta, Wq, Wk, Wv, mask);
  gemm_kva<<<dim3(512), 512, 0, stream>>>(bk, bv, mask);
  attnorm_kernel<<<dim3(32, 8), 256, 0, stream>>>();
  gemm_qy<<<dim3(256), 512, 0, stream>>>(bq, x, out);
}